// Round 6
// baseline (441.331 us; speedup 1.0000x reference)
//
#include <hip/hip_runtime.h>
#include <hip/hip_bf16.h>

#define N_NODES 8192
#define DIN     512
#define DOUT    256
#define ALPHA   0.2f
#define LOG2E   1.4426950408889634f

typedef __bf16 bf16x8 __attribute__((ext_vector_type(8)));
typedef __bf16 bf16x4 __attribute__((ext_vector_type(4)));
typedef float  f32x4  __attribute__((ext_vector_type(4)));
typedef int    i32x4  __attribute__((ext_vector_type(4)));
typedef unsigned u32x4 __attribute__((ext_vector_type(4)));

#define MFMA16 __builtin_amdgcn_mfma_f32_16x16x32_bf16

// ---------------------------------------------------------------------------
// A0: repack weight f32 [512][256] -> wB bf16 fragment layout. Zeroes kmaxkey.
__global__ __launch_bounds__(256) void k_repack_w(const float* __restrict__ w,
                                                  bf16x8* __restrict__ wB,
                                                  unsigned* __restrict__ kmaxkey) {
    if (blockIdx.x == 0 && threadIdx.x == 0) *kmaxkey = 0u;
    int u = blockIdx.x * 256 + threadIdx.x;   // 16384 units
    int lane = u & 63, t = u >> 6;
    int nt = t & 15, kt = t >> 4;
    int k0 = kt * 32 + (lane >> 4) * 8;
    int col = nt * 16 + (lane & 15);
    bf16x8 r;
#pragma unroll
    for (int i = 0; i < 8; ++i) r[i] = (__bf16)w[(size_t)(k0 + i) * DOUT + col];
    wB[u] = r;
}

// ---------------------------------------------------------------------------
// A1 (fused): v = node @ weight in registers; emits vB fragments (LDS bounce),
// Q/K scalars, global K-max.
__global__ __launch_bounds__(256) void k_gemm1f(const float* __restrict__ node,
                                                const bf16x8* __restrict__ wB,
                                                const float* __restrict__ a,
                                                bf16x8* __restrict__ vBo,
                                                float* __restrict__ Q, float* __restrict__ K,
                                                unsigned* __restrict__ kmaxkey) {
    __shared__ __bf16 vsh[32][260];   // +4 pad
    __shared__ float qksh[32][2];
    int lane = threadIdx.x & 63, w = threadIdx.x >> 6;
    int r15 = lane & 15, g = lane >> 4;
    int nh = w & 1, rh = w >> 1;
    int rowbase = blockIdx.x * 32;
    int myrow = rowbase + rh * 16 + r15;
    const float* np = node + (size_t)myrow * DIN + g * 8;

    f32x4 acc[8];
#pragma unroll
    for (int j = 0; j < 8; ++j) acc[j] = (f32x4){0.f, 0.f, 0.f, 0.f};

    f32x4 c0 = *(const f32x4*)np;
    f32x4 c1 = *(const f32x4*)(np + 4);
    f32x4 c2 = *(const f32x4*)(np + 32);
    f32x4 c3 = *(const f32x4*)(np + 36);
    const bf16x8* wp = wB + (size_t)(nh * 8) * 64 + lane;
    bf16x8 fr0 = wp[0], fr1 = wp[64], fr2 = wp[128], fr3 = wp[192];
    bf16x8 fr4 = wp[256], fr5 = wp[320], fr6 = wp[384], fr7 = wp[448];

    for (int kt = 0; kt < 16; ++kt) {
        f32x4 u0 = c0, u1 = c1;
        c0 = c2; c1 = c3;
        if (kt + 2 < 16) {
            c2 = *(const f32x4*)(np + (kt + 2) * 32);
            c3 = *(const f32x4*)(np + (kt + 2) * 32 + 4);
        }
        bf16x8 f0 = fr0, f1 = fr1, f2 = fr2, f3 = fr3;
        bf16x8 f4 = fr4, f5 = fr5, f6 = fr6, f7 = fr7;
        if (kt + 1 < 16) {
            const bf16x8* wn = wB + ((size_t)(kt + 1) * 16 + nh * 8) * 64 + lane;
            fr0 = wn[0]; fr1 = wn[64]; fr2 = wn[128]; fr3 = wn[192];
            fr4 = wn[256]; fr5 = wn[320]; fr6 = wn[384]; fr7 = wn[448];
        }
        bf16x8 af;
#pragma unroll
        for (int i = 0; i < 4; ++i) { af[i] = (__bf16)u0[i]; af[i + 4] = (__bf16)u1[i]; }
        acc[0] = MFMA16(af, f0, acc[0], 0, 0, 0);
        acc[1] = MFMA16(af, f1, acc[1], 0, 0, 0);
        acc[2] = MFMA16(af, f2, acc[2], 0, 0, 0);
        acc[3] = MFMA16(af, f3, acc[3], 0, 0, 0);
        acc[4] = MFMA16(af, f4, acc[4], 0, 0, 0);
        acc[5] = MFMA16(af, f5, acc[5], 0, 0, 0);
        acc[6] = MFMA16(af, f6, acc[6], 0, 0, 0);
        acc[7] = MFMA16(af, f7, acc[7], 0, 0, 0);
    }

    float qp0 = 0.f, qp1 = 0.f, qp2 = 0.f, qp3 = 0.f;
    float kp0 = 0.f, kp1 = 0.f, kp2 = 0.f, kp3 = 0.f;
#pragma unroll
    for (int j = 0; j < 8; ++j) {
        int col = (nh * 8 + j) * 16 + r15;
        float a1 = a[col], a2 = a[DOUT + col];
        qp0 += acc[j][0] * a1; qp1 += acc[j][1] * a1;
        qp2 += acc[j][2] * a1; qp3 += acc[j][3] * a1;
        kp0 += acc[j][0] * a2; kp1 += acc[j][1] * a2;
        kp2 += acc[j][2] * a2; kp3 += acc[j][3] * a2;
    }
#pragma unroll
    for (int m = 1; m < 16; m <<= 1) {
        qp0 += __shfl_xor(qp0, m); qp1 += __shfl_xor(qp1, m);
        qp2 += __shfl_xor(qp2, m); qp3 += __shfl_xor(qp3, m);
        kp0 += __shfl_xor(kp0, m); kp1 += __shfl_xor(kp1, m);
        kp2 += __shfl_xor(kp2, m); kp3 += __shfl_xor(kp3, m);
    }

#pragma unroll
    for (int j = 0; j < 8; ++j)
#pragma unroll
        for (int r = 0; r < 4; ++r)
            vsh[rh * 16 + g * 4 + r][(nh * 8 + j) * 16 + r15] = (__bf16)acc[j][r];
    if (nh == 0 && r15 == 0) {
        int rl = rh * 16 + g * 4;
        qksh[rl + 0][0] = qp0; qksh[rl + 1][0] = qp1; qksh[rl + 2][0] = qp2; qksh[rl + 3][0] = qp3;
        qksh[rl + 0][1] = kp0; qksh[rl + 1][1] = kp1; qksh[rl + 2][1] = kp2; qksh[rl + 3][1] = kp3;
    }
    __syncthreads();
    if (nh == 1 && r15 == 0) {
        int rl = rh * 16 + g * 4;
        int rw = rowbase + rl;
        float q0 = qp0 + qksh[rl + 0][0], q1 = qp1 + qksh[rl + 1][0];
        float q2 = qp2 + qksh[rl + 2][0], q3 = qp3 + qksh[rl + 3][0];
        float k0 = kp0 + qksh[rl + 0][1], k1 = kp1 + qksh[rl + 1][1];
        float k2 = kp2 + qksh[rl + 2][1], k3 = kp3 + qksh[rl + 3][1];
        Q[rw + 0] = q0; Q[rw + 1] = q1; Q[rw + 2] = q2; Q[rw + 3] = q3;
        K[rw + 0] = k0; K[rw + 1] = k1; K[rw + 2] = k2; K[rw + 3] = k3;
        float km = fmaxf(fmaxf(k0, k1), fmaxf(k2, k3));
        unsigned bits = __float_as_uint(km);
        unsigned key = (bits & 0x80000000u) ? ~bits : (bits | 0x80000000u);
        atomicMax(kmaxkey, key);
    }
#pragma unroll
    for (int uu = 0; uu < 4; ++uu) {
        int nt = w * 4 + uu;
        bf16x8 t;
#pragma unroll
        for (int i = 0; i < 8; ++i) t[i] = vsh[g * 8 + i][nt * 16 + r15];
        vBo[((size_t)blockIdx.x * 16 + nt) * 64 + lane] = t;
    }
}

// ---------------------------------------------------------------------------
// B (round-6 REWRITE): barrier-LIGHT fused masked-softmax-numerator GEMM.
// r5 proved the per-step pT convoy had a ~1300cy/step latency floor
// independent of the work inside it. Fix: NO P-exchange. Each wave computes
// P for ALL 64 block rows (4 A-fragments, exp work 4x-duplicated across
// waves -- cheap VALU) x its own 64 output cols (4 vB fragments/step, same
// vB traffic as r3). Zero pT, zero per-step barrier. The adj->bitmask ring
// (r2's coalesced ISSUE8 + ballot PACKB) is fenced by ONE lgkmcnt+s_barrier
// per 4-step group (8/block vs 32): group G consumes slot[G&1] (read once
// into regs at group top), packs slot[(G+1)&1] from regs loaded last group,
// issues loads for G+2 mid-group (in flight across the raw barrier; ~1300cy
// before their ballot-use => latency covered). vB depth-2 reg prefetch as r3.
template<int JS>
__global__ __launch_bounds__(256, 2) void k_attn6(const int* __restrict__ adj,
                                                  const bf16x8* __restrict__ vBg,
                                                  const float* __restrict__ Q,
                                                  const float* __restrict__ K,
                                                  const unsigned* __restrict__ kmaxkey,
                                                  __bf16* __restrict__ accB,
                                                  float* __restrict__ Sp) {
    constexpr int JR  = N_NODES / JS;
    constexpr int BIT = JR / 32;           // k-steps
    constexpr int NG  = BIT / 4;           // 4-step groups
    __shared__ float    Ks[JR];
    __shared__ unsigned Ms2[2][64][12];    // ring: 4 dwords/row + pad (stride 48B)

    const int bid = blockIdx.x;
    const int rb = bid / JS, p = bid % JS;   // p round-robins XCDs (grid%8==0)
    const int lane = threadIdx.x & 63, w = threadIdx.x >> 6;
    const int r15 = lane & 15, g = lane >> 4;
    const int rowbase = rb * 64;
    const int j0 = p * JR;

    // adj mapping (r2, coalesced): instr q covers rows q*8 + w*2 + (lane>>5);
    // lane reads 16B at col ints (lane&31)*4 of the group's 128-int span.
    const int hrow = w * 2 + (lane >> 5);
    const int* abase = adj + (size_t)(rowbase + hrow) * N_NODES + j0 + (lane & 31) * 4;

#define ISSUE8(L, GG) { _Pragma("unroll")                                        \
    for (int q = 0; q < 8; ++q)                                                  \
        L[q] = *(const i32x4*)(abase + (size_t)(q * 8) * N_NODES + (GG) * 128); }

#define PACKB(L, SLOT) { _Pragma("unroll") for (int q = 0; q < 8; ++q) {         \
    unsigned long long b0_ = __ballot(L[q][0] != 0);                             \
    unsigned long long b1_ = __ballot(L[q][1] != 0);                             \
    unsigned long long b2_ = __ballot(L[q][2] != 0);                             \
    unsigned long long b3_ = __ballot(L[q][3] != 0);                             \
    if ((lane & 31) == 0) {                                                      \
        int hi_ = lane >> 5;                                                     \
        u32x4 u_;                                                                \
        u_[0] = hi_ ? (unsigned)(b0_ >> 32) : (unsigned)b0_;                     \
        u_[1] = hi_ ? (unsigned)(b1_ >> 32) : (unsigned)b1_;                     \
        u_[2] = hi_ ? (unsigned)(b2_ >> 32) : (unsigned)b2_;                     \
        u_[3] = hi_ ? (unsigned)(b3_ >> 32) : (unsigned)b3_;                     \
        *(u32x4*)&Ms2[SLOT][q * 8 + hrow][0] = u_;                               \
    } } }

    i32x4 La[8];
    ISSUE8(La, 0)

    for (int s = threadIdx.x * 4; s < JR; s += 1024)
        *(f32x4*)&Ks[s] = *(const f32x4*)&K[j0 + s];

    // per-lane constants for the 4 row-fragments (rows m*16 + r15)
    unsigned kk = *kmaxkey;
    unsigned kb = (kk & 0x80000000u) ? (kk ^ 0x80000000u) : ~kk;
    float kmax = __uint_as_float(kb);
    float A1[4], A2[4];
#pragma unroll
    for (int m = 0; m < 4; ++m) {
        float q = Q[rowbase + m * 16 + r15];
        float t0 = q + kmax;
        float c2 = fmaxf(t0, ALPHA * t0) * LOG2E;
        A1[m] = q * LOG2E - c2;
        A2[m] = ALPHA * q * LOG2E - c2;
    }

    PACKB(La, 0)          // waits the group-0 adj loads; Ks loop overlaps
    ISSUE8(La, 1)

    f32x4 acc[4][4];
#pragma unroll
    for (int m = 0; m < 4; ++m)
#pragma unroll
        for (int n = 0; n < 4; ++n) acc[m][n] = (f32x4){0.f, 0.f, 0.f, 0.f};
    float sl[4] = {0.f, 0.f, 0.f, 0.f};

    const bf16x8* vbp = vBg + ((size_t)(p * BIT) * 16 + w * 4) * 64 + lane;
    bf16x8 vS0 = vbp[0],    vS1 = vbp[64],   vS2 = vbp[128],  vS3 = vbp[192];
    bf16x8 vT0 = vbp[1024], vT1 = vbp[1088], vT2 = vbp[1152], vT3 = vbp[1216];

    // Ks + Ms2 slot0 ready; La(group1) + vS/vT stay in flight (raw barrier).
    asm volatile("s_waitcnt lgkmcnt(0)" ::: "memory");
    __builtin_amdgcn_s_barrier();
    asm volatile("" ::: "memory");

#define STEP(S, V0, V1, V2, V3)                                                 \
    {                                                                           \
        const int itv = it4 + (S);                                              \
        bf16x8 b0 = V0, b1 = V1, b2 = V2, b3 = V3;                              \
        if (itv + 2 < BIT) {                                                    \
            V0 = vbp[(itv + 2) * 1024];       V1 = vbp[(itv + 2) * 1024 + 64];  \
            V2 = vbp[(itv + 2) * 1024 + 128]; V3 = vbp[(itv + 2) * 1024 + 192]; \
        }                                                                       \
        f32x4 q0 = *(const f32x4*)&Ks[itv * 32 + g * 8];                        \
        f32x4 q1 = *(const f32x4*)&Ks[itv * 32 + g * 8 + 4];                    \
        const unsigned bsh = (S) * 8 + g * 2;                                   \
        _Pragma("unroll")                                                       \
        for (int m = 0; m < 4; ++m) {                                           \
            unsigned m0 = Um[m][0] >> bsh, m1 = Um[m][1] >> bsh;                \
            unsigned m2 = Um[m][2] >> bsh, m3 = Um[m][3] >> bsh;                \
            bf16x8 pa;                                                          \
            _Pragma("unroll")                                                   \
            for (int i = 0; i < 8; ++i) {                                       \
                float kj = (i < 4) ? q0[i] : q1[i - 4];                         \
                float f1 = __builtin_fmaf(kj, LOG2E, A1[m]);                    \
                float f2 = __builtin_fmaf(kj, ALPHA * LOG2E, A2[m]);            \
                float pv = __builtin_amdgcn_exp2f(fmaxf(f1, f2));               \
                unsigned mm_ = (i & 3) == 0 ? m0 : ((i & 3) == 1 ? m1 : ((i & 3) == 2 ? m2 : m3)); \
                pv = (mm_ & (1u << (i >> 2))) ? pv : 0.f;                       \
                sl[m] += pv;                                                    \
                pa[i] = (__bf16)pv;                                             \
            }                                                                   \
            acc[m][0] = MFMA16(pa, b0, acc[m][0], 0, 0, 0);                     \
            acc[m][1] = MFMA16(pa, b1, acc[m][1], 0, 0, 0);                     \
            acc[m][2] = MFMA16(pa, b2, acc[m][2], 0, 0, 0);                     \
            acc[m][3] = MFMA16(pa, b3, acc[m][3], 0, 0, 0);                     \
        }                                                                       \
    }

    for (int G = 0; G < NG; ++G) {
        const int it4 = G * 4;
        u32x4 Um[4];
#pragma unroll
        for (int m = 0; m < 4; ++m)
            Um[m] = *(const u32x4*)&Ms2[G & 1][m * 16 + r15][0];
        // pack next group's masks from regs loaded last group (other slot --
        // that slot's readers all passed the previous barrier)
        if (G + 1 < NG) PACKB(La, (G + 1) & 1)
        STEP(0, vS0, vS1, vS2, vS3)
        STEP(1, vT0, vT1, vT2, vT3)
        // issue adj loads for G+2 mid-group: ballot-use is ~2.5 steps +
        // barrier away (>=1300cy) -> HBM latency covered; stays in flight
        // across the raw s_barrier below.
        if (G + 2 < NG) ISSUE8(La, G + 2)
        STEP(2, vS0, vS1, vS2, vS3)
        STEP(3, vT0, vT1, vT2, vT3)
        asm volatile("s_waitcnt lgkmcnt(0)" ::: "memory");
        __builtin_amdgcn_s_barrier();
        asm volatile("" ::: "memory");
    }
#undef STEP
#undef ISSUE8
#undef PACKB

    // row sums: every wave computed identical P -> wave 0 stores.
#pragma unroll
    for (int m = 0; m < 4; ++m) {
        sl[m] += __shfl_xor(sl[m], 16);
        sl[m] += __shfl_xor(sl[m], 32);
    }
    if (w == 0 && lane < 16) {
#pragma unroll
        for (int m = 0; m < 4; ++m)
            Sp[(size_t)p * N_NODES + rowbase + m * 16 + r15] = sl[m];
    }

    // store permuted bf16 partials (r3 layout; k_final un-permutes)
    __bf16* apb = accB + ((size_t)p * N_NODES + rowbase) * DOUT;
#pragma unroll
    for (int m = 0; m < 4; ++m)
#pragma unroll
        for (int r = 0; r < 4; ++r) {
            bf16x4 t2;
#pragma unroll
            for (int n = 0; n < 4; ++n) t2[n] = (__bf16)acc[m][n][r];
            *(bf16x4*)&apb[(size_t)(m * 16 + g * 4 + r) * DOUT + w * 64 + r15 * 4] = t2;
        }
}

// ---------------------------------------------------------------------------
// C: combine bf16 partials (permuted layout), softmax denom, leaky-relu,
// L2-normalize, +bias. Wave per row; un-permute on store (r3 mapping).
template<int JS>
__global__ __launch_bounds__(256) void k_final(const __bf16* __restrict__ accB,
                                               const float* __restrict__ Sp,
                                               const float* __restrict__ bias,
                                               float* __restrict__ out) {
    int lane = threadIdx.x & 63, wv = threadIdx.x >> 6;
    int row = blockIdx.x * 4 + wv;
    float s = 0.f;
    f32x4 av = (f32x4){0.f, 0.f, 0.f, 0.f};
#pragma unroll
    for (int pp = 0; pp < JS; ++pp) {
        bf16x4 t = *(const bf16x4*)&accB[((size_t)pp * N_NODES + row) * DOUT + lane * 4];
#pragma unroll
        for (int j = 0; j < 4; ++j) av[j] += (float)t[j];
        s += Sp[(size_t)pp * N_NODES + row];
    }
    float inv = 1.0f / fmaxf(s, 1e-30f);
    f32x4 o;
#pragma unroll
    for (int j = 0; j < 4; ++j) {
        float x = av[j] * inv;
        o[j] = fmaxf(x, ALPHA * x);
    }
    float sq = o[0] * o[0] + o[1] * o[1] + o[2] * o[2] + o[3] * o[3];
#pragma unroll
    for (int m = 1; m < 64; m <<= 1) sq += __shfl_xor(sq, m);
    float innrm = 1.0f / fmaxf(sqrtf(sq), 1e-12f);
#pragma unroll
    for (int j = 0; j < 4; ++j) {
        int col = (lane >> 4) * 64 + j * 16 + (lane & 15);
        out[(size_t)row * DOUT + col] = o[j] * innrm + bias[col];
    }
}

// ---------------------------------------------------------------------------
extern "C" void kernel_launch(void* const* d_in, const int* in_sizes, int n_in,
                              void* d_out, int out_size, void* d_ws, size_t ws_size,
                              hipStream_t stream) {
    const float* node   = (const float*)d_in[0];
    const int*   adj    = (const int*)d_in[1];
    const float* weight = (const float*)d_in[2];
    const float* a      = (const float*)d_in[3];
    const float* bias   = (const float*)d_in[4];
    float* out = (float*)d_out;

    const size_t fixed  = 4522240;                 // wB 256K + vB 4M + Q/K 64K + kmax
    const size_t per_js = 32768 + (size_t)N_NODES * DOUT * 2;   // Sp + accB(bf16)
    int js = (ws_size >= fixed + 8 * per_js) ? 8 : 4;

    char* ws = (char*)d_ws;
    bf16x8*   wB      = (bf16x8*)(ws);
    bf16x8*   vB      = (bf16x8*)(ws + 262144);
    float*    Q       = (float*)(ws + 4456448);
    float*    K       = (float*)(ws + 4489216);
    unsigned* kmaxkey = (unsigned*)(ws + 4521984);
    float*    Sp      = (float*)(ws + fixed);
    __bf16*   accB    = (__bf16*)(ws + fixed + (size_t)js * 32768);

    k_repack_w<<<dim3(64),  dim3(256), 0, stream>>>(weight, wB, kmaxkey);
    k_gemm1f  <<<dim3(256), dim3(256), 0, stream>>>(node, wB, a, vB, Q, K, kmaxkey);
    if (js == 8) {
        k_attn6<8><<<dim3(128 * 8), dim3(256), 0, stream>>>(adj, vB, Q, K, kmaxkey, accB, Sp);
        k_final<8><<<dim3(2048), dim3(256), 0, stream>>>(accB, Sp, bias, out);
    } else {
        k_attn6<4><<<dim3(128 * 4), dim3(256), 0, stream>>>(adj, vB, Q, K, kmaxkey, accB, Sp);
        k_final<4><<<dim3(2048), dim3(256), 0, stream>>>(accB, Sp, bias, out);
    }
}

// Round 7
// 177.792 us; speedup vs baseline: 2.4823x; 2.4823x over previous
//
#include <hip/hip_runtime.h>
#include <hip/hip_bf16.h>

#define N_NODES 8192
#define DIN     512
#define DOUT    256
#define ALPHA   0.2f
#define LOG2E   1.4426950408889634f

typedef __bf16 bf16x8 __attribute__((ext_vector_type(8)));
typedef __bf16 bf16x4 __attribute__((ext_vector_type(4)));
typedef float  f32x4  __attribute__((ext_vector_type(4)));
typedef int    i32x4  __attribute__((ext_vector_type(4)));
typedef unsigned u32x4 __attribute__((ext_vector_type(4)));

#define MFMA16 __builtin_amdgcn_mfma_f32_16x16x32_bf16

// ---------------------------------------------------------------------------
// A0: repack weight f32 [512][256] -> wB bf16 fragment layout. Zeroes kmaxkey.
__global__ __launch_bounds__(256) void k_repack_w(const float* __restrict__ w,
                                                  bf16x8* __restrict__ wB,
                                                  unsigned* __restrict__ kmaxkey) {
    if (blockIdx.x == 0 && threadIdx.x == 0) *kmaxkey = 0u;
    int u = blockIdx.x * 256 + threadIdx.x;   // 16384 units
    int lane = u & 63, t = u >> 6;
    int nt = t & 15, kt = t >> 4;
    int k0 = kt * 32 + (lane >> 4) * 8;
    int col = nt * 16 + (lane & 15);
    bf16x8 r;
#pragma unroll
    for (int i = 0; i < 8; ++i) r[i] = (__bf16)w[(size_t)(k0 + i) * DOUT + col];
    wB[u] = r;
}

// ---------------------------------------------------------------------------
// A1 (fused): v = node @ weight in registers; emits vB fragments (LDS bounce),
// Q/K scalars, global K-max.
__global__ __launch_bounds__(256) void k_gemm1f(const float* __restrict__ node,
                                                const bf16x8* __restrict__ wB,
                                                const float* __restrict__ a,
                                                bf16x8* __restrict__ vBo,
                                                float* __restrict__ Q, float* __restrict__ K,
                                                unsigned* __restrict__ kmaxkey) {
    __shared__ __bf16 vsh[32][260];   // +4 pad
    __shared__ float qksh[32][2];
    int lane = threadIdx.x & 63, w = threadIdx.x >> 6;
    int r15 = lane & 15, g = lane >> 4;
    int nh = w & 1, rh = w >> 1;
    int rowbase = blockIdx.x * 32;
    int myrow = rowbase + rh * 16 + r15;
    const float* np = node + (size_t)myrow * DIN + g * 8;

    f32x4 acc[8];
#pragma unroll
    for (int j = 0; j < 8; ++j) acc[j] = (f32x4){0.f, 0.f, 0.f, 0.f};

    f32x4 c0 = *(const f32x4*)np;
    f32x4 c1 = *(const f32x4*)(np + 4);
    f32x4 c2 = *(const f32x4*)(np + 32);
    f32x4 c3 = *(const f32x4*)(np + 36);
    const bf16x8* wp = wB + (size_t)(nh * 8) * 64 + lane;
    bf16x8 fr0 = wp[0], fr1 = wp[64], fr2 = wp[128], fr3 = wp[192];
    bf16x8 fr4 = wp[256], fr5 = wp[320], fr6 = wp[384], fr7 = wp[448];

    for (int kt = 0; kt < 16; ++kt) {
        f32x4 u0 = c0, u1 = c1;
        c0 = c2; c1 = c3;
        if (kt + 2 < 16) {
            c2 = *(const f32x4*)(np + (kt + 2) * 32);
            c3 = *(const f32x4*)(np + (kt + 2) * 32 + 4);
        }
        bf16x8 f0 = fr0, f1 = fr1, f2 = fr2, f3 = fr3;
        bf16x8 f4 = fr4, f5 = fr5, f6 = fr6, f7 = fr7;
        if (kt + 1 < 16) {
            const bf16x8* wn = wB + ((size_t)(kt + 1) * 16 + nh * 8) * 64 + lane;
            fr0 = wn[0]; fr1 = wn[64]; fr2 = wn[128]; fr3 = wn[192];
            fr4 = wn[256]; fr5 = wn[320]; fr6 = wn[384]; fr7 = wn[448];
        }
        bf16x8 af;
#pragma unroll
        for (int i = 0; i < 4; ++i) { af[i] = (__bf16)u0[i]; af[i + 4] = (__bf16)u1[i]; }
        acc[0] = MFMA16(af, f0, acc[0], 0, 0, 0);
        acc[1] = MFMA16(af, f1, acc[1], 0, 0, 0);
        acc[2] = MFMA16(af, f2, acc[2], 0, 0, 0);
        acc[3] = MFMA16(af, f3, acc[3], 0, 0, 0);
        acc[4] = MFMA16(af, f4, acc[4], 0, 0, 0);
        acc[5] = MFMA16(af, f5, acc[5], 0, 0, 0);
        acc[6] = MFMA16(af, f6, acc[6], 0, 0, 0);
        acc[7] = MFMA16(af, f7, acc[7], 0, 0, 0);
    }

    float qp0 = 0.f, qp1 = 0.f, qp2 = 0.f, qp3 = 0.f;
    float kp0 = 0.f, kp1 = 0.f, kp2 = 0.f, kp3 = 0.f;
#pragma unroll
    for (int j = 0; j < 8; ++j) {
        int col = (nh * 8 + j) * 16 + r15;
        float a1 = a[col], a2 = a[DOUT + col];
        qp0 += acc[j][0] * a1; qp1 += acc[j][1] * a1;
        qp2 += acc[j][2] * a1; qp3 += acc[j][3] * a1;
        kp0 += acc[j][0] * a2; kp1 += acc[j][1] * a2;
        kp2 += acc[j][2] * a2; kp3 += acc[j][3] * a2;
    }
#pragma unroll
    for (int m = 1; m < 16; m <<= 1) {
        qp0 += __shfl_xor(qp0, m); qp1 += __shfl_xor(qp1, m);
        qp2 += __shfl_xor(qp2, m); qp3 += __shfl_xor(qp3, m);
        kp0 += __shfl_xor(kp0, m); kp1 += __shfl_xor(kp1, m);
        kp2 += __shfl_xor(kp2, m); kp3 += __shfl_xor(kp3, m);
    }

#pragma unroll
    for (int j = 0; j < 8; ++j)
#pragma unroll
        for (int r = 0; r < 4; ++r)
            vsh[rh * 16 + g * 4 + r][(nh * 8 + j) * 16 + r15] = (__bf16)acc[j][r];
    if (nh == 0 && r15 == 0) {
        int rl = rh * 16 + g * 4;
        qksh[rl + 0][0] = qp0; qksh[rl + 1][0] = qp1; qksh[rl + 2][0] = qp2; qksh[rl + 3][0] = qp3;
        qksh[rl + 0][1] = kp0; qksh[rl + 1][1] = kp1; qksh[rl + 2][1] = kp2; qksh[rl + 3][1] = kp3;
    }
    __syncthreads();
    if (nh == 1 && r15 == 0) {
        int rl = rh * 16 + g * 4;
        int rw = rowbase + rl;
        float q0 = qp0 + qksh[rl + 0][0], q1 = qp1 + qksh[rl + 1][0];
        float q2 = qp2 + qksh[rl + 2][0], q3 = qp3 + qksh[rl + 3][0];
        float k0 = kp0 + qksh[rl + 0][1], k1 = kp1 + qksh[rl + 1][1];
        float k2 = kp2 + qksh[rl + 2][1], k3 = kp3 + qksh[rl + 3][1];
        Q[rw + 0] = q0; Q[rw + 1] = q1; Q[rw + 2] = q2; Q[rw + 3] = q3;
        K[rw + 0] = k0; K[rw + 1] = k1; K[rw + 2] = k2; K[rw + 3] = k3;
        float km = fmaxf(fmaxf(k0, k1), fmaxf(k2, k3));
        unsigned bits = __float_as_uint(km);
        unsigned key = (bits & 0x80000000u) ? ~bits : (bits | 0x80000000u);
        atomicMax(kmaxkey, key);
    }
#pragma unroll
    for (int uu = 0; uu < 4; ++uu) {
        int nt = w * 4 + uu;
        bf16x8 t;
#pragma unroll
        for (int i = 0; i < 8; ++i) t[i] = vsh[g * 8 + i][nt * 16 + r15];
        vBo[((size_t)blockIdx.x * 16 + nt) * 64 + lane] = t;
    }
}

// ---------------------------------------------------------------------------
// P (r5, verified): standalone adj -> bitmask pack. Fill-shaped stream:
// half-wave task = one (row, 128-col group); lane reads i32x4 (wave = 1 KB
// contiguous), 4 ballots -> u32x4 stored by lanes 0/32. Dword e of group,
// bit k <-> col-in-group 4k+e. Msg layout [p][row][DW dwords].
template<int JS>
__global__ __launch_bounds__(256) void k_pack(const int* __restrict__ adj,
                                              unsigned* __restrict__ Msg) {
    constexpr int GPS = 64 / JS;          // 128-col groups per slice
    constexpr int DW  = GPS * 4;          // mask dwords per row per slice
    const int lane = threadIdx.x & 63;
    const int hw   = threadIdx.x >> 5;    // half-wave slot 0..7
    const int l31  = threadIdx.x & 31;
    for (int it = 0; it < 32; ++it) {     // 2048 blocks x 8 hw x 32 = 524288 tasks
        int task = (it * 2048 + blockIdx.x) * 8 + hw;
        int row = task >> 6, grp = task & 63;
        i32x4 v = *(const i32x4*)(adj + (size_t)task * 128 + l31 * 4);
        unsigned long long b0 = __ballot(v[0] != 0);
        unsigned long long b1 = __ballot(v[1] != 0);
        unsigned long long b2 = __ballot(v[2] != 0);
        unsigned long long b3 = __ballot(v[3] != 0);
        if (l31 == 0) {
            int hi = lane >> 5;
            u32x4 u;
            u[0] = hi ? (unsigned)(b0 >> 32) : (unsigned)b0;
            u[1] = hi ? (unsigned)(b1 >> 32) : (unsigned)b1;
            u[2] = hi ? (unsigned)(b2 >> 32) : (unsigned)b2;
            u[3] = hi ? (unsigned)(b3 >> 32) : (unsigned)b3;
            int p = grp / GPS, gd = grp % GPS;
            *(u32x4*)&Msg[((size_t)p * N_NODES + row) * DW + gd * 4] = u;
        }
    }
}

// ---------------------------------------------------------------------------
// B (round-7): BARRIER-FREE masked-softmax-numerator GEMM, register-safe.
// r6's decomposition (wave computes P for all 64 rows x its own 64 cols;
// exp 4x-duplicated across waves; zero pT, zero main-loop barriers) but with
// the adj ring + ballots REPLACED by the precomputed Msg bitmask (k_pack),
// loaded once into LDS Ms in the prologue (8 KB coalesced, r5's loader).
// Removes La[8] (32 VGPR) -> live set ~150 VGPR, no spill (r6 spilled
// ~1.3 GB scratch at VGPR_Count=128). Plain launch_bounds(256): no
// occupancy-forcing arg. Waves free-run; vB slice (512 KB) is L2-resident
// per XCD (p == bid%8); per-wave vB depth-2 register prefetch as r3/r6.
template<int JS>
__global__ __launch_bounds__(256) void k_attn7(const bf16x8* __restrict__ vBg,
                                               const float* __restrict__ Q,
                                               const float* __restrict__ K,
                                               const unsigned* __restrict__ kmaxkey,
                                               const unsigned* __restrict__ Msg,
                                               __bf16* __restrict__ accB,
                                               float* __restrict__ Sp) {
    constexpr int JR   = N_NODES / JS;
    constexpr int BIT  = JR / 32;          // k-steps (= mask dwords per row)
    constexpr int NG   = BIT / 4;          // 4-step groups
    constexpr int MSTR = BIT + 4;          // pad: stride 144B (JS=8), 16B-aligned
    __shared__ float    Ks[JR];
    __shared__ unsigned Ms[64][MSTR];

    const int bid = blockIdx.x;
    const int rb = bid / JS, p = bid % JS;   // p round-robins XCDs (grid%8==0)
    const int lane = threadIdx.x & 63, w = threadIdx.x >> 6;
    const int r15 = lane & 15, g = lane >> 4;
    const int rowbase = rb * 64;
    const int j0 = p * JR;

    for (int s = threadIdx.x * 4; s < JR; s += 1024)
        *(f32x4*)&Ks[s] = *(const f32x4*)&K[j0 + s];

    // mask prologue: 64 rows x BIT dwords, contiguous in Msg
    const unsigned* msrc = Msg + ((size_t)p * N_NODES + rowbase) * BIT;
#pragma unroll
    for (int v = 0; v < BIT / 16; ++v) {
        int idx = v * 256 + threadIdx.x;
        int row = idx / (BIT / 4), q4 = idx % (BIT / 4);
        *(u32x4*)&Ms[row][q4 * 4] = *(const u32x4*)&msrc[(size_t)row * BIT + q4 * 4];
    }

    // per-lane constants for the 4 row-fragments (rows m*16 + r15)
    unsigned kk = *kmaxkey;
    unsigned kb = (kk & 0x80000000u) ? (kk ^ 0x80000000u) : ~kk;
    float kmax = __uint_as_float(kb);
    float A1[4], A2[4];
#pragma unroll
    for (int m = 0; m < 4; ++m) {
        float q = Q[rowbase + m * 16 + r15];
        float t0 = q + kmax;
        float c2 = fmaxf(t0, ALPHA * t0) * LOG2E;
        A1[m] = q * LOG2E - c2;
        A2[m] = ALPHA * q * LOG2E - c2;
    }

    f32x4 acc[4][4];
#pragma unroll
    for (int m = 0; m < 4; ++m)
#pragma unroll
        for (int n = 0; n < 4; ++n) acc[m][n] = (f32x4){0.f, 0.f, 0.f, 0.f};
    float sl[4] = {0.f, 0.f, 0.f, 0.f};

    const bf16x8* vbp = vBg + ((size_t)(p * BIT) * 16 + w * 4) * 64 + lane;
    bf16x8 vS0 = vbp[0],    vS1 = vbp[64],   vS2 = vbp[128],  vS3 = vbp[192];
    bf16x8 vT0 = vbp[1024], vT1 = vbp[1088], vT2 = vbp[1152], vT3 = vbp[1216];

    __syncthreads();   // Ks + Ms ready; only sync in the kernel

#define STEP(S, V0, V1, V2, V3)                                                 \
    {                                                                           \
        const int itv = it4 + (S);                                              \
        bf16x8 b0 = V0, b1 = V1, b2 = V2, b3 = V3;                              \
        if (itv + 2 < BIT) {                                                    \
            V0 = vbp[(itv + 2) * 1024];       V1 = vbp[(itv + 2) * 1024 + 64];  \
            V2 = vbp[(itv + 2) * 1024 + 128]; V3 = vbp[(itv + 2) * 1024 + 192]; \
        }                                                                       \
        f32x4 q0 = *(const f32x4*)&Ks[itv * 32 + g * 8];                        \
        f32x4 q1 = *(const f32x4*)&Ks[itv * 32 + g * 8 + 4];                    \
        const unsigned bsh = (S) * 8 + g * 2;                                   \
        _Pragma("unroll")                                                       \
        for (int m = 0; m < 4; ++m) {                                           \
            unsigned m0 = Um[m][0] >> bsh, m1 = Um[m][1] >> bsh;                \
            unsigned m2 = Um[m][2] >> bsh, m3 = Um[m][3] >> bsh;                \
            bf16x8 pa;                                                          \
            _Pragma("unroll")                                                   \
            for (int i = 0; i < 8; ++i) {                                       \
                float kj = (i < 4) ? q0[i] : q1[i - 4];                         \
                float f1 = __builtin_fmaf(kj, LOG2E, A1[m]);                    \
                float f2 = __builtin_fmaf(kj, ALPHA * LOG2E, A2[m]);            \
                float pv = __builtin_amdgcn_exp2f(fmaxf(f1, f2));               \
                unsigned mm_ = (i & 3) == 0 ? m0 : ((i & 3) == 1 ? m1 : ((i & 3) == 2 ? m2 : m3)); \
                pv = (mm_ & (1u << (i >> 2))) ? pv : 0.f;                       \
                sl[m] += pv;                                                    \
                pa[i] = (__bf16)pv;                                             \
            }                                                                   \
            acc[m][0] = MFMA16(pa, b0, acc[m][0], 0, 0, 0);                     \
            acc[m][1] = MFMA16(pa, b1, acc[m][1], 0, 0, 0);                     \
            acc[m][2] = MFMA16(pa, b2, acc[m][2], 0, 0, 0);                     \
            acc[m][3] = MFMA16(pa, b3, acc[m][3], 0, 0, 0);                     \
        }                                                                       \
    }

    for (int G = 0; G < NG; ++G) {
        const int it4 = G * 4;
        u32x4 Um[4];
#pragma unroll
        for (int m = 0; m < 4; ++m)
            Um[m] = *(const u32x4*)&Ms[m * 16 + r15][it4];
        STEP(0, vS0, vS1, vS2, vS3)
        STEP(1, vT0, vT1, vT2, vT3)
        STEP(2, vS0, vS1, vS2, vS3)
        STEP(3, vT0, vT1, vT2, vT3)
    }
#undef STEP

    // row sums: every wave computed identical P -> wave 0 stores.
#pragma unroll
    for (int m = 0; m < 4; ++m) {
        sl[m] += __shfl_xor(sl[m], 16);
        sl[m] += __shfl_xor(sl[m], 32);
    }
    if (w == 0 && lane < 16) {
#pragma unroll
        for (int m = 0; m < 4; ++m)
            Sp[(size_t)p * N_NODES + rowbase + m * 16 + r15] = sl[m];
    }

    // store permuted bf16 partials (r6 layout, verified; k_final un-permutes)
    __bf16* apb = accB + ((size_t)p * N_NODES + rowbase) * DOUT;
#pragma unroll
    for (int m = 0; m < 4; ++m)
#pragma unroll
        for (int r = 0; r < 4; ++r) {
            bf16x4 t2;
#pragma unroll
            for (int n = 0; n < 4; ++n) t2[n] = (__bf16)acc[m][n][r];
            *(bf16x4*)&apb[(size_t)(m * 16 + g * 4 + r) * DOUT + w * 64 + r15 * 4] = t2;
        }
}

// ---------------------------------------------------------------------------
// C: combine bf16 partials (permuted layout), softmax denom, leaky-relu,
// L2-normalize, +bias. Wave per row; un-permute on store (r6 mapping).
template<int JS>
__global__ __launch_bounds__(256) void k_final(const __bf16* __restrict__ accB,
                                               const float* __restrict__ Sp,
                                               const float* __restrict__ bias,
                                               float* __restrict__ out) {
    int lane = threadIdx.x & 63, wv = threadIdx.x >> 6;
    int row = blockIdx.x * 4 + wv;
    float s = 0.f;
    f32x4 av = (f32x4){0.f, 0.f, 0.f, 0.f};
#pragma unroll
    for (int pp = 0; pp < JS; ++pp) {
        bf16x4 t = *(const bf16x4*)&accB[((size_t)pp * N_NODES + row) * DOUT + lane * 4];
#pragma unroll
        for (int j = 0; j < 4; ++j) av[j] += (float)t[j];
        s += Sp[(size_t)pp * N_NODES + row];
    }
    float inv = 1.0f / fmaxf(s, 1e-30f);
    f32x4 o;
#pragma unroll
    for (int j = 0; j < 4; ++j) {
        float x = av[j] * inv;
        o[j] = fmaxf(x, ALPHA * x);
    }
    float sq = o[0] * o[0] + o[1] * o[1] + o[2] * o[2] + o[3] * o[3];
#pragma unroll
    for (int m = 1; m < 64; m <<= 1) sq += __shfl_xor(sq, m);
    float innrm = 1.0f / fmaxf(sqrtf(sq), 1e-12f);
#pragma unroll
    for (int j = 0; j < 4; ++j) {
        int col = (lane >> 4) * 64 + j * 16 + (lane & 15);
        out[(size_t)row * DOUT + col] = o[j] * innrm + bias[col];
    }
}

// ---------------------------------------------------------------------------
extern "C" void kernel_launch(void* const* d_in, const int* in_sizes, int n_in,
                              void* d_out, int out_size, void* d_ws, size_t ws_size,
                              hipStream_t stream) {
    const float* node   = (const float*)d_in[0];
    const int*   adj    = (const int*)d_in[1];
    const float* weight = (const float*)d_in[2];
    const float* a      = (const float*)d_in[3];
    const float* bias   = (const float*)d_in[4];
    float* out = (float*)d_out;

    const size_t fixed  = 4522240;                 // wB 256K + vB 4M + Q/K 64K + kmax
    const size_t per_js = 32768 + (size_t)N_NODES * DOUT * 2;   // Sp + accB(bf16)
    const size_t msgsz  = (size_t)N_NODES * N_NODES / 8;        // 8 MB bitmask
    int js = (ws_size >= fixed + 8 * per_js + msgsz) ? 8 : 4;

    char* ws = (char*)d_ws;
    bf16x8*   wB      = (bf16x8*)(ws);
    bf16x8*   vB      = (bf16x8*)(ws + 262144);
    float*    Q       = (float*)(ws + 4456448);
    float*    K       = (float*)(ws + 4489216);
    unsigned* kmaxkey = (unsigned*)(ws + 4521984);
    float*    Sp      = (float*)(ws + fixed);
    __bf16*   accB    = (__bf16*)(ws + fixed + (size_t)js * 32768);
    unsigned* Msg     = (unsigned*)(ws + fixed + (size_t)js * per_js);

    k_repack_w<<<dim3(64),  dim3(256), 0, stream>>>(weight, wB, kmaxkey);
    k_gemm1f  <<<dim3(256), dim3(256), 0, stream>>>(node, wB, a, vB, Q, K, kmaxkey);
    if (js == 8) {
        k_pack<8> <<<dim3(2048), dim3(256), 0, stream>>>(adj, Msg);
        k_attn7<8><<<dim3(128 * 8), dim3(256), 0, stream>>>(vB, Q, K, kmaxkey, Msg, accB, Sp);
        k_final<8><<<dim3(2048), dim3(256), 0, stream>>>(accB, Sp, bias, out);
    } else {
        k_pack<4> <<<dim3(2048), dim3(256), 0, stream>>>(adj, Msg);
        k_attn7<4><<<dim3(128 * 4), dim3(256), 0, stream>>>(vB, Q, K, kmaxkey, Msg, accB, Sp);
        k_final<4><<<dim3(2048), dim3(256), 0, stream>>>(accB, Sp, bias, out);
    }
}

// Round 8
// 114.438 us; speedup vs baseline: 3.8565x; 1.5536x over previous
//
#include <hip/hip_runtime.h>
#include <hip/hip_bf16.h>

#define N_NODES 8192
#define DIN     512
#define DOUT    256
#define ALPHA   0.2f
#define LOG2E   1.4426950408889634f

typedef __bf16 bf16x8 __attribute__((ext_vector_type(8)));
typedef __bf16 bf16x4 __attribute__((ext_vector_type(4)));
typedef __bf16 bf16x2 __attribute__((ext_vector_type(2)));
typedef float  f32x4  __attribute__((ext_vector_type(4)));
typedef int    i32x4  __attribute__((ext_vector_type(4)));
typedef unsigned u32x4 __attribute__((ext_vector_type(4)));

#define MFMA16 __builtin_amdgcn_mfma_f32_16x16x32_bf16

// ---------------------------------------------------------------------------
// A0: repack weight f32 [512][256] -> wB bf16 fragment layout. Zeroes kmaxkey.
__global__ __launch_bounds__(256) void k_repack_w(const float* __restrict__ w,
                                                  bf16x8* __restrict__ wB,
                                                  unsigned* __restrict__ kmaxkey) {
    if (blockIdx.x == 0 && threadIdx.x == 0) *kmaxkey = 0u;
    int u = blockIdx.x * 256 + threadIdx.x;   // 16384 units
    int lane = u & 63, t = u >> 6;
    int nt = t & 15, kt = t >> 4;
    int k0 = kt * 32 + (lane >> 4) * 8;
    int col = nt * 16 + (lane & 15);
    bf16x8 r;
#pragma unroll
    for (int i = 0; i < 8; ++i) r[i] = (__bf16)w[(size_t)(k0 + i) * DOUT + col];
    wB[u] = r;
}

// ---------------------------------------------------------------------------
// A1 (fused): v = node @ weight in registers; emits vB fragments (LDS bounce),
// Q/K scalars, global K-max.
__global__ __launch_bounds__(256) void k_gemm1f(const float* __restrict__ node,
                                                const bf16x8* __restrict__ wB,
                                                const float* __restrict__ a,
                                                bf16x8* __restrict__ vBo,
                                                float* __restrict__ Q, float* __restrict__ K,
                                                unsigned* __restrict__ kmaxkey) {
    __shared__ __bf16 vsh[32][260];   // +4 pad
    __shared__ float qksh[32][2];
    int lane = threadIdx.x & 63, w = threadIdx.x >> 6;
    int r15 = lane & 15, g = lane >> 4;
    int nh = w & 1, rh = w >> 1;
    int rowbase = blockIdx.x * 32;
    int myrow = rowbase + rh * 16 + r15;
    const float* np = node + (size_t)myrow * DIN + g * 8;

    f32x4 acc[8];
#pragma unroll
    for (int j = 0; j < 8; ++j) acc[j] = (f32x4){0.f, 0.f, 0.f, 0.f};

    f32x4 c0 = *(const f32x4*)np;
    f32x4 c1 = *(const f32x4*)(np + 4);
    f32x4 c2 = *(const f32x4*)(np + 32);
    f32x4 c3 = *(const f32x4*)(np + 36);
    const bf16x8* wp = wB + (size_t)(nh * 8) * 64 + lane;
    bf16x8 fr0 = wp[0], fr1 = wp[64], fr2 = wp[128], fr3 = wp[192];
    bf16x8 fr4 = wp[256], fr5 = wp[320], fr6 = wp[384], fr7 = wp[448];

    for (int kt = 0; kt < 16; ++kt) {
        f32x4 u0 = c0, u1 = c1;
        c0 = c2; c1 = c3;
        if (kt + 2 < 16) {
            c2 = *(const f32x4*)(np + (kt + 2) * 32);
            c3 = *(const f32x4*)(np + (kt + 2) * 32 + 4);
        }
        bf16x8 f0 = fr0, f1 = fr1, f2 = fr2, f3 = fr3;
        bf16x8 f4 = fr4, f5 = fr5, f6 = fr6, f7 = fr7;
        if (kt + 1 < 16) {
            const bf16x8* wn = wB + ((size_t)(kt + 1) * 16 + nh * 8) * 64 + lane;
            fr0 = wn[0]; fr1 = wn[64]; fr2 = wn[128]; fr3 = wn[192];
            fr4 = wn[256]; fr5 = wn[320]; fr6 = wn[384]; fr7 = wn[448];
        }
        bf16x8 af;
#pragma unroll
        for (int i = 0; i < 4; ++i) { af[i] = (__bf16)u0[i]; af[i + 4] = (__bf16)u1[i]; }
        acc[0] = MFMA16(af, f0, acc[0], 0, 0, 0);
        acc[1] = MFMA16(af, f1, acc[1], 0, 0, 0);
        acc[2] = MFMA16(af, f2, acc[2], 0, 0, 0);
        acc[3] = MFMA16(af, f3, acc[3], 0, 0, 0);
        acc[4] = MFMA16(af, f4, acc[4], 0, 0, 0);
        acc[5] = MFMA16(af, f5, acc[5], 0, 0, 0);
        acc[6] = MFMA16(af, f6, acc[6], 0, 0, 0);
        acc[7] = MFMA16(af, f7, acc[7], 0, 0, 0);
    }

    float qp0 = 0.f, qp1 = 0.f, qp2 = 0.f, qp3 = 0.f;
    float kp0 = 0.f, kp1 = 0.f, kp2 = 0.f, kp3 = 0.f;
#pragma unroll
    for (int j = 0; j < 8; ++j) {
        int col = (nh * 8 + j) * 16 + r15;
        float a1 = a[col], a2 = a[DOUT + col];
        qp0 += acc[j][0] * a1; qp1 += acc[j][1] * a1;
        qp2 += acc[j][2] * a1; qp3 += acc[j][3] * a1;
        kp0 += acc[j][0] * a2; kp1 += acc[j][1] * a2;
        kp2 += acc[j][2] * a2; kp3 += acc[j][3] * a2;
    }
#pragma unroll
    for (int m = 1; m < 16; m <<= 1) {
        qp0 += __shfl_xor(qp0, m); qp1 += __shfl_xor(qp1, m);
        qp2 += __shfl_xor(qp2, m); qp3 += __shfl_xor(qp3, m);
        kp0 += __shfl_xor(kp0, m); kp1 += __shfl_xor(kp1, m);
        kp2 += __shfl_xor(kp2, m); kp3 += __shfl_xor(kp3, m);
    }

#pragma unroll
    for (int j = 0; j < 8; ++j)
#pragma unroll
        for (int r = 0; r < 4; ++r)
            vsh[rh * 16 + g * 4 + r][(nh * 8 + j) * 16 + r15] = (__bf16)acc[j][r];
    if (nh == 0 && r15 == 0) {
        int rl = rh * 16 + g * 4;
        qksh[rl + 0][0] = qp0; qksh[rl + 1][0] = qp1; qksh[rl + 2][0] = qp2; qksh[rl + 3][0] = qp3;
        qksh[rl + 0][1] = kp0; qksh[rl + 1][1] = kp1; qksh[rl + 2][1] = kp2; qksh[rl + 3][1] = kp3;
    }
    __syncthreads();
    if (nh == 1 && r15 == 0) {
        int rl = rh * 16 + g * 4;
        int rw = rowbase + rl;
        float q0 = qp0 + qksh[rl + 0][0], q1 = qp1 + qksh[rl + 1][0];
        float q2 = qp2 + qksh[rl + 2][0], q3 = qp3 + qksh[rl + 3][0];
        float k0 = kp0 + qksh[rl + 0][1], k1 = kp1 + qksh[rl + 1][1];
        float k2 = kp2 + qksh[rl + 2][1], k3 = kp3 + qksh[rl + 3][1];
        Q[rw + 0] = q0; Q[rw + 1] = q1; Q[rw + 2] = q2; Q[rw + 3] = q3;
        K[rw + 0] = k0; K[rw + 1] = k1; K[rw + 2] = k2; K[rw + 3] = k3;
        float km = fmaxf(fmaxf(k0, k1), fmaxf(k2, k3));
        unsigned bits = __float_as_uint(km);
        unsigned key = (bits & 0x80000000u) ? ~bits : (bits | 0x80000000u);
        atomicMax(kmaxkey, key);
    }
#pragma unroll
    for (int uu = 0; uu < 4; ++uu) {
        int nt = w * 4 + uu;
        bf16x8 t;
#pragma unroll
        for (int i = 0; i < 8; ++i) t[i] = vsh[g * 8 + i][nt * 16 + r15];
        vBo[((size_t)blockIdx.x * 16 + nt) * 64 + lane] = t;
    }
}

// ---------------------------------------------------------------------------
// B (round-8): 512-thread / 128-row fused masked-softmax-numerator GEMM.
// 8 waves; wave w: computes exp for rows [w*16,w*16+16) (1 A-frag, r3's
// per-wave cost, no duplication), exchanges via exp-pipelined pT (store
// af(t-1) -> barrier -> read 8 pa frags -> compute af(t+1) in MFMA shadow),
// owns cols [w*32,(w+1)*32) (2 B-frags/step). vB traffic per step covers
// 128 rows -> 256 MB aggregate (half of r3). Convoy steps per CU: 64 (half).
// adj fused: r2's coalesced ISSUE8 + ballot PACKB into a JIT ring Ms2[2],
// fenced by the per-step barriers (pack at group G step0 -> slot (G+1)&1
// first read after G step3's barrier: 3 barriers of slack; loads issued at
// step1 of G-1: ~3 steps in flight).
template<int JS>
__global__ __launch_bounds__(512) void k_attn8(const int* __restrict__ adj,
                                               const bf16x8* __restrict__ vBg,
                                               const float* __restrict__ Q,
                                               const float* __restrict__ K,
                                               const unsigned* __restrict__ kmaxkey,
                                               __bf16* __restrict__ accB,
                                               float* __restrict__ Sp) {
    constexpr int JR  = N_NODES / JS;
    constexpr int BIT = JR / 32;           // k-steps
    constexpr int NG  = BIT / 4;           // 4-step groups
    __shared__ float    Ks[JR];
    __shared__ unsigned Ms2[2][128][4];    // ring: 4 mask dwords per row
    __shared__ bf16x8   pT[2][8][64];

    const int bid = blockIdx.x;
    const int rb = bid / JS, p = bid % JS;   // p round-robins XCDs (grid%8==0)
    const int tid = threadIdx.x;
    const int lane = tid & 63, w = tid >> 6;
    const int r15 = lane & 15, g = lane >> 4;
    const int rowbase = rb * 128;
    const int j0 = p * JR;
    const int prow = rowbase + w * 16 + r15;

    // adj mapping: instr q covers local rows q*16 + hrow, hrow = w*2+(lane>>5)
    // (8 waves -> hrow 0..15; q 0..7 -> rows 0..127). Lane reads 16B at col
    // ints (lane&31)*4 of the group's 128-int span. Coalesced 512B runs.
    const int hrow = w * 2 + (lane >> 5);
    const int* abase = adj + (size_t)(rowbase + hrow) * N_NODES + j0 + (lane & 31) * 4;

#define ISSUE8(L, GG) { _Pragma("unroll")                                        \
    for (int q = 0; q < 8; ++q)                                                  \
        L[q] = *(const i32x4*)(abase + (size_t)(q * 16) * N_NODES + (GG) * 128); }

#define PACKB(L, SLOT) { _Pragma("unroll") for (int q = 0; q < 8; ++q) {         \
    unsigned long long b0_ = __ballot(L[q][0] != 0);                             \
    unsigned long long b1_ = __ballot(L[q][1] != 0);                             \
    unsigned long long b2_ = __ballot(L[q][2] != 0);                             \
    unsigned long long b3_ = __ballot(L[q][3] != 0);                             \
    if ((lane & 31) == 0) {                                                      \
        int hi_ = lane >> 5;                                                     \
        u32x4 u_;                                                                \
        u_[0] = hi_ ? (unsigned)(b0_ >> 32) : (unsigned)b0_;                     \
        u_[1] = hi_ ? (unsigned)(b1_ >> 32) : (unsigned)b1_;                     \
        u_[2] = hi_ ? (unsigned)(b2_ >> 32) : (unsigned)b2_;                     \
        u_[3] = hi_ ? (unsigned)(b3_ >> 32) : (unsigned)b3_;                     \
        *(u32x4*)&Ms2[SLOT][q * 16 + w * 2 + hi_][0] = u_;                       \
    } } }

    i32x4 La[8];
    ISSUE8(La, 0)

    for (int s = tid * 4; s < JR; s += 2048)
        *(f32x4*)&Ks[s] = *(const f32x4*)&K[j0 + s];

    float qi = Q[prow];
    unsigned kk = *kmaxkey;
    unsigned kb = (kk & 0x80000000u) ? (kk ^ 0x80000000u) : ~kk;
    float kmax = __uint_as_float(kb);
    float t0 = qi + kmax;
    float c2 = fmaxf(t0, ALPHA * t0) * LOG2E;
    float A1 = qi * LOG2E - c2;
    float A2 = ALPHA * qi * LOG2E - c2;

    PACKB(La, 0)            // waits group-0 adj loads (Ks/Q math overlapped)
    ISSUE8(La, 1)

    f32x4 acc[8][2];
#pragma unroll
    for (int m = 0; m < 8; ++m) {
        acc[m][0] = (f32x4){0.f, 0.f, 0.f, 0.f};
        acc[m][1] = (f32x4){0.f, 0.f, 0.f, 0.f};
    }
    float sl = 0.f;

    const bf16x8* vbp = vBg + ((size_t)(p * BIT) * 16 + w * 2) * 64 + lane;
    bf16x8 vS0 = vbp[0],    vS1 = vbp[64];
    bf16x8 vT0 = vbp[1024], vT1 = vbp[1088];

    // Ks + Ms2 slot0 visible; group-1 adj loads + vS/vT stay in flight.
    asm volatile("s_waitcnt lgkmcnt(0)" ::: "memory");
    __builtin_amdgcn_s_barrier();
    asm volatile("" ::: "memory");

    u32x4 Uc = *(const u32x4*)&Ms2[0][w * 16 + r15][0];

#define EXPBLK(WN4, SN, kstep)                                                  \
    {                                                                           \
        f32x4 q0 = *(const f32x4*)&Ks[(kstep) * 32 + g * 8];                    \
        f32x4 q1 = *(const f32x4*)&Ks[(kstep) * 32 + g * 8 + 4];                \
        unsigned bsh = (SN) * 8 + g * 2;                                        \
        unsigned m0 = (WN4)[0] >> bsh, m1 = (WN4)[1] >> bsh;                    \
        unsigned m2 = (WN4)[2] >> bsh, m3 = (WN4)[3] >> bsh;                    \
        _Pragma("unroll")                                                       \
        for (int i = 0; i < 8; ++i) {                                           \
            float kj = (i < 4) ? q0[i] : q1[i - 4];                             \
            float f1 = __builtin_fmaf(kj, LOG2E, A1);                           \
            float f2 = __builtin_fmaf(kj, ALPHA * LOG2E, A2);                   \
            float pv = __builtin_amdgcn_exp2f(fmaxf(f1, f2));                   \
            unsigned mm_ = (i & 3) == 0 ? m0 : ((i & 3) == 1 ? m1 : ((i & 3) == 2 ? m2 : m3)); \
            pv = (mm_ & (1u << (i >> 2))) ? pv : 0.f;                           \
            sl += pv;                                                           \
            afc[i] = (__bf16)pv;                                                \
        }                                                                       \
    }

    bf16x8 afc;
    EXPBLK(Uc, 0, 0)

#define STEP(UU, SN, V0, V1, BUF, itv, ...)                                     \
    {                                                                           \
        bf16x8 b0 = V0, b1 = V1;                                                \
        if ((itv) + 2 < BIT) {                                                  \
            V0 = vbp[((itv) + 2) * 1024];                                       \
            V1 = vbp[((itv) + 2) * 1024 + 64];                                  \
        }                                                                       \
        pT[BUF][w][lane] = afc;                                                 \
        asm volatile("s_waitcnt lgkmcnt(0)" ::: "memory");                      \
        __builtin_amdgcn_s_barrier();                                           \
        asm volatile("" ::: "memory");                                         \
        bf16x8 pa0 = pT[BUF][0][lane], pa1 = pT[BUF][1][lane];                  \
        bf16x8 pa2 = pT[BUF][2][lane], pa3 = pT[BUF][3][lane];                  \
        bf16x8 pa4 = pT[BUF][4][lane], pa5 = pT[BUF][5][lane];                  \
        bf16x8 pa6 = pT[BUF][6][lane], pa7 = pT[BUF][7][lane];                  \
        __VA_ARGS__                                                             \
        if ((itv) + 1 < BIT) EXPBLK(UU, SN, (itv) + 1)                          \
        acc[0][0] = MFMA16(pa0, b0, acc[0][0], 0, 0, 0);                        \
        acc[0][1] = MFMA16(pa0, b1, acc[0][1], 0, 0, 0);                        \
        acc[1][0] = MFMA16(pa1, b0, acc[1][0], 0, 0, 0);                        \
        acc[1][1] = MFMA16(pa1, b1, acc[1][1], 0, 0, 0);                        \
        acc[2][0] = MFMA16(pa2, b0, acc[2][0], 0, 0, 0);                        \
        acc[2][1] = MFMA16(pa2, b1, acc[2][1], 0, 0, 0);                        \
        acc[3][0] = MFMA16(pa3, b0, acc[3][0], 0, 0, 0);                        \
        acc[3][1] = MFMA16(pa3, b1, acc[3][1], 0, 0, 0);                        \
        acc[4][0] = MFMA16(pa4, b0, acc[4][0], 0, 0, 0);                        \
        acc[4][1] = MFMA16(pa4, b1, acc[4][1], 0, 0, 0);                        \
        acc[5][0] = MFMA16(pa5, b0, acc[5][0], 0, 0, 0);                        \
        acc[5][1] = MFMA16(pa5, b1, acc[5][1], 0, 0, 0);                        \
        acc[6][0] = MFMA16(pa6, b0, acc[6][0], 0, 0, 0);                        \
        acc[6][1] = MFMA16(pa6, b1, acc[6][1], 0, 0, 0);                        \
        acc[7][0] = MFMA16(pa7, b0, acc[7][0], 0, 0, 0);                        \
        acc[7][1] = MFMA16(pa7, b1, acc[7][1], 0, 0, 0);                        \
    }

    for (int G = 0; G < NG; ++G) {
        const int it4 = G * 4;
        u32x4 Un = Uc;
        STEP(Uc, 1, vS0, vS1, 0, it4 + 0, if (G + 1 < NG) PACKB(La, (G + 1) & 1))
        STEP(Uc, 2, vT0, vT1, 1, it4 + 1, if (G + 2 < NG) ISSUE8(La, G + 2))
        STEP(Uc, 3, vS0, vS1, 0, it4 + 2, )
        STEP(Un, 0, vT0, vT1, 1, it4 + 3,
             if (G + 1 < NG) Un = *(const u32x4*)&Ms2[(G + 1) & 1][w * 16 + r15][0];)
        Uc = Un;
    }
#undef STEP
#undef EXPBLK
#undef ISSUE8
#undef PACKB

    // row sums for this wave's 16 rows
    sl += __shfl_xor(sl, 16);
    sl += __shfl_xor(sl, 32);
    if (g == 0) Sp[(size_t)p * N_NODES + prow] = sl;

    // store permuted bf16 partials: phys col = w*32 + r15*2 + n
    __bf16* apb = accB + ((size_t)p * N_NODES + rowbase) * DOUT;
#pragma unroll
    for (int m = 0; m < 8; ++m)
#pragma unroll
        for (int r = 0; r < 4; ++r) {
            bf16x2 t2;
            t2[0] = (__bf16)acc[m][0][r];
            t2[1] = (__bf16)acc[m][1][r];
            *(bf16x2*)&apb[(size_t)(m * 16 + g * 4 + r) * DOUT + w * 32 + r15 * 2] = t2;
        }
}

// ---------------------------------------------------------------------------
// C: combine bf16 partials (permuted layout), softmax denom, leaky-relu,
// L2-normalize, +bias. Wave per row; un-permute on store:
// phys = w*32 + r15*2 + n  ->  logical col = (w*2+n)*16 + r15.
template<int JS>
__global__ __launch_bounds__(256) void k_final(const __bf16* __restrict__ accB,
                                               const float* __restrict__ Sp,
                                               const float* __restrict__ bias,
                                               float* __restrict__ out) {
    int lane = threadIdx.x & 63, wv = threadIdx.x >> 6;
    int row = blockIdx.x * 4 + wv;
    float s = 0.f;
    f32x4 av = (f32x4){0.f, 0.f, 0.f, 0.f};
#pragma unroll
    for (int pp = 0; pp < JS; ++pp) {
        bf16x4 t = *(const bf16x4*)&accB[((size_t)pp * N_NODES + row) * DOUT + lane * 4];
#pragma unroll
        for (int j = 0; j < 4; ++j) av[j] += (float)t[j];
        s += Sp[(size_t)pp * N_NODES + row];
    }
    float inv = 1.0f / fmaxf(s, 1e-30f);
    f32x4 o;
#pragma unroll
    for (int j = 0; j < 4; ++j) {
        float x = av[j] * inv;
        o[j] = fmaxf(x, ALPHA * x);
    }
    float sq = o[0] * o[0] + o[1] * o[1] + o[2] * o[2] + o[3] * o[3];
#pragma unroll
    for (int m = 1; m < 64; m <<= 1) sq += __shfl_xor(sq, m);
    float innrm = 1.0f / fmaxf(sqrtf(sq), 1e-12f);
#pragma unroll
    for (int j = 0; j < 4; ++j) {
        int ph = lane * 4 + j;
        int col = (((ph >> 5) * 2 + (ph & 1)) << 4) + ((ph & 31) >> 1);
        out[(size_t)row * DOUT + col] = o[j] * innrm + bias[col];
    }
}

// ---------------------------------------------------------------------------
extern "C" void kernel_launch(void* const* d_in, const int* in_sizes, int n_in,
                              void* d_out, int out_size, void* d_ws, size_t ws_size,
                              hipStream_t stream) {
    const float* node   = (const float*)d_in[0];
    const int*   adj    = (const int*)d_in[1];
    const float* weight = (const float*)d_in[2];
    const float* a      = (const float*)d_in[3];
    const float* bias   = (const float*)d_in[4];
    float* out = (float*)d_out;

    const size_t fixed  = 4522240;                 // wB 256K + vB 4M + Q/K 64K + kmax
    const size_t per_js = 32768 + (size_t)N_NODES * DOUT * 2;   // Sp + accB(bf16)
    int js = (ws_size >= fixed + 8 * per_js) ? 8 : 4;

    char* ws = (char*)d_ws;
    bf16x8*   wB      = (bf16x8*)(ws);
    bf16x8*   vB      = (bf16x8*)(ws + 262144);
    float*    Q       = (float*)(ws + 4456448);
    float*    K       = (float*)(ws + 4489216);
    unsigned* kmaxkey = (unsigned*)(ws + 4521984);
    float*    Sp      = (float*)(ws + fixed);
    __bf16*   accB    = (__bf16*)(ws + fixed + (size_t)js * 32768);

    k_repack_w<<<dim3(64),  dim3(256), 0, stream>>>(weight, wB, kmaxkey);
    k_gemm1f  <<<dim3(256), dim3(256), 0, stream>>>(node, wB, a, vB, Q, K, kmaxkey);
    if (js == 8) {
        k_attn8<8><<<dim3(64 * 8), dim3(512), 0, stream>>>(adj, vB, Q, K, kmaxkey, accB, Sp);
        k_final<8><<<dim3(2048), dim3(256), 0, stream>>>(accB, Sp, bias, out);
    } else {
        k_attn8<4><<<dim3(64 * 4), dim3(512), 0, stream>>>(adj, vB, Q, K, kmaxkey, accB, Sp);
        k_final<4><<<dim3(2048), dim3(256), 0, stream>>>(accB, Sp, bias, out);
    }
}